// Round 12
// baseline (209.423 us; speedup 1.0000x reference)
//
#include <hip/hip_runtime.h>

#define NN 50000
#define EE 800000
#define DD 128
#define BN_EPS 1e-5f
#define XCONV_B 3125    // N*D/8/256
#define BIN_BLOCKS 200
#define BIN_EDGES 4000  // per block; 200*4000 == EE
#define NBUCK 3125      // ceil(50000/16): 16-row buckets
#define BCAP 512        // bucket capacity (mean 256, ~16 sigma headroom)
#define NREP 32         // BN-stat replica count
#define GEMM_B 782      // ceil(NN/64) for gemm2
#define LDA 136         // padded LDS A-tile stride (bf16): 272B -> 2-way banks

typedef __attribute__((ext_vector_type(8))) short bf16x8;
typedef __attribute__((ext_vector_type(4))) float f32x4;
typedef __attribute__((ext_vector_type(8))) unsigned short u16x8;

__device__ inline unsigned short f2bf(float f) {  // RNE fp32 -> bf16
  unsigned int u = __float_as_uint(f);
  u = (u + 0x7fffu + ((u >> 16) & 1u)) >> 16;
  return (unsigned short)u;
}
__device__ inline float bf2f(unsigned short b) {
  return __uint_as_float(((unsigned int)b) << 16);
}

// ---------------------------------------------------------------------------
// Memory plan (byte offsets into d_out, 25.6MB; scratch dead before k_bnrelu
// overwrites d_out with the fp32 result):
//   [0, +12500B)    bcur[NBUCK] bucket cursors
//   [4.0M, 16.8M)   xb  = bf16(x)                  (dies after k_aggemm1)
//   [16.8M, 23.2M)  bbuf = u32[NBUCK*BCAP] packed (row&15)<<16|col
//   [23.28M,+32KB)  W1b; [23.36M,+32KB) W2b
//   [23.5M, +64KB)  reps: sum1[NREP][128] | sumsq1 | sum2 | sumsq2
// d_ws (25.6MB + 4KB): h1b | h2b | stats tail: scale2[128] | shift2[128]
// 6 dispatches. Lessons pinned: grid.sync ~100us/sync (R8); launch gap
// ~13us/dispatch (R7-R9); aggemm gather is latency-bound — occupancy is
// grid-capped, so bucket granularity sets waves/CU (R10: 782blk=28%,
// R11: 1563blk=28.5%; here 3125blk targets ~24 waves/CU peak).
// ---------------------------------------------------------------------------

// K0: fused prep — x->bf16, W1->bf16, W2->bf16, zero bcur + stat replicas
__global__ __launch_bounds__(256) void k_prep(const float* __restrict__ x,
                                              const float* __restrict__ W1,
                                              const float* __restrict__ W2,
                                              unsigned short* __restrict__ xb,
                                              unsigned short* __restrict__ W1b,
                                              unsigned short* __restrict__ W2b,
                                              int* __restrict__ bcur,
                                              float* __restrict__ reps) {
  const int b = blockIdx.x;
  const int t = threadIdx.x;
  if (b < XCONV_B) {
    const int gid = b * 256 + t;
    const float4 v0 = ((const float4*)x)[gid * 2];
    const float4 v1 = ((const float4*)x)[gid * 2 + 1];
    ushort4 o0, o1;
    o0.x = f2bf(v0.x); o0.y = f2bf(v0.y); o0.z = f2bf(v0.z); o0.w = f2bf(v0.w);
    o1.x = f2bf(v1.x); o1.y = f2bf(v1.y); o1.z = f2bf(v1.z); o1.w = f2bf(v1.w);
    ((ushort4*)xb)[gid * 2] = o0;
    ((ushort4*)xb)[gid * 2 + 1] = o1;
    if (gid < NBUCK) bcur[gid] = 0;
    if (gid < 4 * NREP * DD) reps[gid] = 0.0f;  // 16384 floats
  } else if (b < XCONV_B + 16) {
    const int gid = (b - XCONV_B) * 256 + t;
    const float4 v = ((const float4*)W1)[gid];
    ushort4 o;
    o.x = f2bf(v.x); o.y = f2bf(v.y); o.z = f2bf(v.z); o.w = f2bf(v.w);
    ((ushort4*)W1b)[gid] = o;
  } else {
    const int gid = (b - XCONV_B - 16) * 256 + t;
    const float4 v = ((const float4*)W2)[gid];
    ushort4 o;
    o.x = f2bf(v.x); o.y = f2bf(v.y); o.z = f2bf(v.z); o.w = f2bf(v.w);
    ((ushort4*)W2b)[gid] = o;
  }
}

// K1: bin edges into fixed-capacity 16-row buckets (block-private segments
// via one global reservation per bucket — HBM write amp stays 1x).
__global__ __launch_bounds__(256) void k_bin0(const int* __restrict__ rows,
                                              const int* __restrict__ cols,
                                              int* __restrict__ bcur,
                                              unsigned int* __restrict__ bbuf) {
  __shared__ int hist[NBUCK];
  __shared__ int lbase[NBUCK];
  const int t = threadIdx.x;
  for (int i = t; i < NBUCK; i += 256) hist[i] = 0;
  __syncthreads();
  const int e0 = blockIdx.x * BIN_EDGES;
  int er[16], ec[16];
#pragma unroll
  for (int i = 0; i < 16; ++i) {
    const int idx = t + i * 256;
    if (idx < BIN_EDGES) {
      er[i] = rows[e0 + idx];
      ec[i] = cols[e0 + idx];
      atomicAdd(&hist[er[i] >> 4], 1);
    }
  }
  __syncthreads();
  for (int i = t; i < NBUCK; i += 256) {
    const int c = hist[i];
    lbase[i] = (c > 0) ? atomicAdd(&bcur[i], c) : 0;
    hist[i] = 0;  // reuse as local placement cursor
  }
  __syncthreads();
#pragma unroll
  for (int i = 0; i < 16; ++i) {
    const int idx = t + i * 256;
    if (idx < BIN_EDGES) {
      const int bk = er[i] >> 4;
      const int lp = lbase[bk] + atomicAdd(&hist[bk], 1);
      if (lp < BCAP)  // statistically impossible overflow; memory-safety clamp
        bbuf[(size_t)bk * BCAP + lp] =
            ((unsigned)(er[i] & 15) << 16) | (unsigned)ec[i];
    }
  }
}

// K2: FUSED per-bucket aggregation + GEMM1. Block = bucket b = rows
// [16b,16b+16), 128 threads (2 waves). Phase A: LDS counting sort +
// wave-per-row gather with 4-deep load pipelining; aggregated bf16 rows land
// in a padded LDS tile. Phase B: MFMA GEMM — wave wv computes all 16 rows x
// cols [wv*64,wv*64+64) (A from LDS, B=W1b from global); epilogue writes
// h1b + BN1 replica stats.
__global__ __launch_bounds__(128) void k_aggemm1(
    const unsigned short* __restrict__ xb, const float* __restrict__ eps,
    const int* __restrict__ bcnt, const unsigned int* __restrict__ bbuf,
    const unsigned short* __restrict__ W, const float* __restrict__ bias,
    unsigned short* __restrict__ outb, float* __restrict__ sum1r,
    float* __restrict__ sumsq1r) {
  __shared__ unsigned short scols[BCAP];   // 1KB sorted col ids
  __shared__ unsigned short sA[16 * LDA];  // 4.4KB padded A tile (bf16)
  __shared__ int rcnt[16];
  __shared__ int roff[17];
  __shared__ int sscan[128];
  __shared__ float bsum[DD];
  __shared__ float bsq[DD];
  const int t = threadIdx.x;
  const int bk = blockIdx.x;
  const int wv = t >> 6;       // 0..1
  const int lane = t & 63;
  const int sub = lane >> 4;   // 0..3 (== quad in phase B)
  const int l16 = lane & 15;

  int n = bcnt[bk];
  n = n < BCAP ? n : BCAP;
  if (t < 16) rcnt[t] = 0;
  bsum[t] = 0.f;
  bsq[t] = 0.f;
  __syncthreads();

  // ---- phase A1: load bucket entries + per-row count
  unsigned int ent[4];
  int nl = 0;
  for (int i = t; i < n; i += 128) {
    const unsigned int e = bbuf[(size_t)bk * BCAP + i];
    ent[nl++] = e;
    atomicAdd(&rcnt[e >> 16], 1);
  }
  __syncthreads();
  // exclusive scan of 16 row-counts
  sscan[t] = (t < 16) ? rcnt[t] : 0;
  __syncthreads();
#pragma unroll
  for (int off = 1; off < 16; off <<= 1) {
    const int v = (t >= off) ? sscan[t - off] : 0;
    __syncthreads();
    sscan[t] += v;
    __syncthreads();
  }
  if (t < 16) {
    roff[t] = sscan[t] - rcnt[t];
    rcnt[t] = 0;  // reuse as placement cursor
  }
  if (t == 15) roff[16] = sscan[15];
  __syncthreads();
  // place col ids row-sorted
  for (int i = 0; i < nl; ++i) {
    const int r = ent[i] >> 16;
    const int pos = roff[r] + atomicAdd(&rcnt[r], 1);
    scols[pos] = (unsigned short)(ent[i] & 0xffffu);
  }
  __syncthreads();

  // ---- phase A2: gather-aggregate; wave wv owns rows wv, wv+2, ...
  {
    const float s = 1.0f + eps[0];
    for (int r = wv; r < 16; r += 2) {
      const int v = bk * 16 + r;
      float acc[8];
#pragma unroll
      for (int j = 0; j < 8; ++j) acc[j] = 0.f;
      if (v < NN) {
        if (sub == 0) {
          const u16x8 a = *(const u16x8*)(xb + (size_t)v * DD + l16 * 8);
#pragma unroll
          for (int j = 0; j < 8; ++j) acc[j] = s * bf2f(a[j]);
        }
        const int beg = roff[r];
        const int end = roff[r + 1];
        int i = beg + sub;
        // 4-deep load pipeline per sub (16 rows in flight per wave)
        for (; i + 12 < end; i += 16) {
          const int u0 = scols[i];
          const int u1 = scols[i + 4];
          const int u2 = scols[i + 8];
          const int u3 = scols[i + 12];
          const u16x8 a = *(const u16x8*)(xb + (size_t)u0 * DD + l16 * 8);
          const u16x8 b = *(const u16x8*)(xb + (size_t)u1 * DD + l16 * 8);
          const u16x8 c = *(const u16x8*)(xb + (size_t)u2 * DD + l16 * 8);
          const u16x8 d = *(const u16x8*)(xb + (size_t)u3 * DD + l16 * 8);
#pragma unroll
          for (int j = 0; j < 8; ++j)
            acc[j] += (bf2f(a[j]) + bf2f(b[j])) + (bf2f(c[j]) + bf2f(d[j]));
        }
        for (; i + 4 < end; i += 8) {
          const int u0 = scols[i];
          const int u1 = scols[i + 4];
          const u16x8 a = *(const u16x8*)(xb + (size_t)u0 * DD + l16 * 8);
          const u16x8 b = *(const u16x8*)(xb + (size_t)u1 * DD + l16 * 8);
#pragma unroll
          for (int j = 0; j < 8; ++j) acc[j] += bf2f(a[j]) + bf2f(b[j]);
        }
        if (i < end) {
          const int u = scols[i];
          const u16x8 a = *(const u16x8*)(xb + (size_t)u * DD + l16 * 8);
#pragma unroll
          for (int j = 0; j < 8; ++j) acc[j] += bf2f(a[j]);
        }
      }
#pragma unroll
      for (int j = 0; j < 8; ++j) {
        acc[j] += __shfl_xor(acc[j], 16);
        acc[j] += __shfl_xor(acc[j], 32);
      }
      if (sub == 0) {
        u16x8 o;
#pragma unroll
        for (int j = 0; j < 8; ++j) o[j] = f2bf(acc[j]);
        *(u16x8*)(&sA[r * LDA + l16 * 8]) = o;  // 2-way bank alias: free
      }
    }
  }
  __syncthreads();

  // ---- phase B: MFMA GEMM; wave wv: rows 0-15 x cols [wv*64, wv*64+64)
  f32x4 acc[4];
#pragma unroll
  for (int nn = 0; nn < 4; ++nn) acc[nn] = (f32x4){0.f, 0.f, 0.f, 0.f};
#pragma unroll
  for (int kk = 0; kk < 4; ++kk) {
    const bf16x8 af = *(const bf16x8*)(&sA[l16 * LDA + kk * 32 + sub * 8]);
#pragma unroll
    for (int nn = 0; nn < 4; ++nn) {
      const bf16x8 bf = *(const bf16x8*)(
          W + (size_t)(wv * 64 + nn * 16 + l16) * DD + sub * 8 + kk * 32);
      acc[nn] = __builtin_amdgcn_mfma_f32_16x16x32_bf16(af, bf, acc[nn], 0, 0, 0);
    }
  }
  const int orow0 = bk * 16 + sub * 4;
#pragma unroll
  for (int nn = 0; nn < 4; ++nn) {
    const int col = wv * 64 + nn * 16 + l16;
    const float bv = bias[col];
    float sv = 0.f, qv = 0.f;
#pragma unroll
    for (int r = 0; r < 4; ++r) {
      const int row = orow0 + r;
      if (row < NN) {
        const float o = acc[nn][r] + bv;
        outb[(size_t)row * DD + col] = f2bf(o);
        sv += o; qv += o * o;
      }
    }
    sv += __shfl_xor(sv, 16); qv += __shfl_xor(qv, 16);
    sv += __shfl_xor(sv, 32); qv += __shfl_xor(qv, 32);
    if (sub == 0) { atomicAdd(&bsum[col], sv); atomicAdd(&bsq[col], qv); }
  }
  __syncthreads();
  {
    const int rep = (bk & (NREP - 1)) * DD;
    atomicAdd(&sum1r[rep + t], bsum[t]);
    atomicAdd(&sumsq1r[rep + t], bsq[t]);
  }
}

// ---------------------------------------------------------------------------
// GEMM2: collapse sum1 replicas -> BN1 scale/shift in-block; A=relu(BN1(h1b))
// on the fly; out = h2b bf16; BN2 stats into replicas.
// ---------------------------------------------------------------------------
__global__ __launch_bounds__(256) void k_gemm2(const unsigned short* __restrict__ A,
                                               const float* __restrict__ sum1r,
                                               const float* __restrict__ sumsq1r,
                                               const float* __restrict__ gamma,
                                               const float* __restrict__ beta,
                                               const unsigned short* __restrict__ W,
                                               const float* __restrict__ bias,
                                               unsigned short* __restrict__ outb,
                                               float* __restrict__ sum2r,
                                               float* __restrict__ sumsq2r) {
  __shared__ float lsc[DD];
  __shared__ float lsh[DD];
  __shared__ float bsum[DD];
  __shared__ float bsq[DD];
  const int tid = threadIdx.x;
  const int wv = tid >> 6;
  const int lane = tid & 63;
  const int quad = lane >> 4;
  const int l16 = lane & 15;
  if (tid < DD) {
    float sm = 0.f, qm = 0.f;
#pragma unroll
    for (int r = 0; r < NREP; ++r) {
      sm += sum1r[r * DD + tid];
      qm += sumsq1r[r * DD + tid];
    }
    const float inv_n = 1.0f / (float)NN;
    const float mean = sm * inv_n;
    const float var = qm * inv_n - mean * mean;
    const float s = gamma[tid] * rsqrtf(var + BN_EPS);
    lsc[tid] = s;
    lsh[tid] = beta[tid] - mean * s;
    bsum[tid] = 0.f;
    bsq[tid] = 0.f;
  }
  __syncthreads();

  const int rowbase = blockIdx.x * 64 + wv * 16 + l16;
  const int arow = rowbase < NN ? rowbase : NN - 1;
  const unsigned short* aptr = A + (size_t)arow * DD + quad * 8;

  f32x4 acc[8];
#pragma unroll
  for (int n = 0; n < 8; ++n) acc[n] = (f32x4){0.f, 0.f, 0.f, 0.f};
#pragma unroll
  for (int kk = 0; kk < 4; ++kk) {
    const int kbase = kk * 32 + quad * 8;
    const u16x8 a = *(const u16x8*)(aptr + kk * 32);
    const float4 s0 = *(const float4*)&lsc[kbase];
    const float4 s1 = *(const float4*)&lsc[kbase + 4];
    const float4 h0 = *(const float4*)&lsh[kbase];
    const float4 h1 = *(const float4*)&lsh[kbase + 4];
    bf16x8 af;
    af[0] = (short)f2bf(fmaxf(fmaf(s0.x, bf2f(a[0]), h0.x), 0.f));
    af[1] = (short)f2bf(fmaxf(fmaf(s0.y, bf2f(a[1]), h0.y), 0.f));
    af[2] = (short)f2bf(fmaxf(fmaf(s0.z, bf2f(a[2]), h0.z), 0.f));
    af[3] = (short)f2bf(fmaxf(fmaf(s0.w, bf2f(a[3]), h0.w), 0.f));
    af[4] = (short)f2bf(fmaxf(fmaf(s1.x, bf2f(a[4]), h1.x), 0.f));
    af[5] = (short)f2bf(fmaxf(fmaf(s1.y, bf2f(a[5]), h1.y), 0.f));
    af[6] = (short)f2bf(fmaxf(fmaf(s1.z, bf2f(a[6]), h1.z), 0.f));
    af[7] = (short)f2bf(fmaxf(fmaf(s1.w, bf2f(a[7]), h1.w), 0.f));
#pragma unroll
    for (int n = 0; n < 8; ++n) {
      const bf16x8 bf =
          *(const bf16x8*)(W + (size_t)(n * 16 + l16) * DD + kbase);
      acc[n] = __builtin_amdgcn_mfma_f32_16x16x32_bf16(af, bf, acc[n], 0, 0, 0);
    }
  }
  const int orow0 = blockIdx.x * 64 + wv * 16 + quad * 4;
#pragma unroll
  for (int n = 0; n < 8; ++n) {
    const int col = n * 16 + l16;
    const float bv = bias[col];
    float sv = 0.f, qv = 0.f;
#pragma unroll
    for (int r = 0; r < 4; ++r) {
      const int row = orow0 + r;
      if (row < NN) {
        const float o = acc[n][r] + bv;
        outb[(size_t)row * DD + col] = f2bf(o);
        sv += o; qv += o * o;
      }
    }
    sv += __shfl_xor(sv, 16); qv += __shfl_xor(qv, 16);
    sv += __shfl_xor(sv, 32); qv += __shfl_xor(qv, 32);
    if (quad == 0) { atomicAdd(&bsum[col], sv); atomicAdd(&bsq[col], qv); }
  }
  __syncthreads();
  if (tid < DD) {
    const int rep = (blockIdx.x & (NREP - 1)) * DD;
    atomicAdd(&sum2r[rep + tid], bsum[tid]);
    atomicAdd(&sumsq2r[rep + tid], bsq[tid]);
  }
}

// K4: collapse BN2 replicas -> scale/shift in d_ws (replicas live in d_out,
// which k_bnrelu overwrites — must happen first).
__global__ void k_bnstats2(const float* __restrict__ sum2r,
                           const float* __restrict__ sumsq2r,
                           const float* __restrict__ gamma,
                           const float* __restrict__ beta,
                           float* __restrict__ scale,
                           float* __restrict__ shift) {
  const int c = threadIdx.x;
  float sm = 0.f, qm = 0.f;
#pragma unroll
  for (int r = 0; r < NREP; ++r) {
    sm += sum2r[r * DD + c];
    qm += sumsq2r[r * DD + c];
  }
  const float inv_n = 1.0f / (float)NN;
  const float mean = sm * inv_n;
  const float var = qm * inv_n - mean * mean;
  const float sc = gamma[c] * rsqrtf(var + BN_EPS);
  scale[c] = sc;
  shift[c] = beta[c] - mean * sc;
}

// K5: final BN2 + ReLU -> fp32 out
__global__ __launch_bounds__(256) void k_bnrelu(const unsigned short* __restrict__ in,
                                                const float* __restrict__ scale,
                                                const float* __restrict__ shift,
                                                float* __restrict__ out) {
  __shared__ float lsc[DD];
  __shared__ float lsh[DD];
  const int t = threadIdx.x;
  if (t < DD) {
    lsc[t] = scale[t];
    lsh[t] = shift[t];
  }
  __syncthreads();
  const int gid = blockIdx.x * 256 + t;
  const int c = (gid & 15) * 8;
  const u16x8 a = ((const u16x8*)in)[gid];
  const float4 sc0 = *(const float4*)&lsc[c];
  const float4 sc1 = *(const float4*)&lsc[c + 4];
  const float4 sh0 = *(const float4*)&lsh[c];
  const float4 sh1 = *(const float4*)&lsh[c + 4];
  float4 o0, o1;
  o0.x = fmaxf(fmaf(sc0.x, bf2f(a[0]), sh0.x), 0.f);
  o0.y = fmaxf(fmaf(sc0.y, bf2f(a[1]), sh0.y), 0.f);
  o0.z = fmaxf(fmaf(sc0.z, bf2f(a[2]), sh0.z), 0.f);
  o0.w = fmaxf(fmaf(sc0.w, bf2f(a[3]), sh0.w), 0.f);
  o1.x = fmaxf(fmaf(sc1.x, bf2f(a[4]), sh1.x), 0.f);
  o1.y = fmaxf(fmaf(sc1.y, bf2f(a[5]), sh1.y), 0.f);
  o1.z = fmaxf(fmaf(sc1.z, bf2f(a[6]), sh1.z), 0.f);
  o1.w = fmaxf(fmaf(sc1.w, bf2f(a[7]), sh1.w), 0.f);
  ((float4*)out)[gid * 2] = o0;
  ((float4*)out)[gid * 2 + 1] = o1;
}

// ---------------------------------------------------------------------------
extern "C" void kernel_launch(void* const* d_in, const int* in_sizes, int n_in,
                              void* d_out, int out_size, void* d_ws, size_t ws_size,
                              hipStream_t stream) {
  const float* x = (const float*)d_in[0];
  const int* ei = (const int*)d_in[1];
  const float* eps = (const float*)d_in[2];
  const float* W1 = (const float*)d_in[3];
  const float* b1 = (const float*)d_in[4];
  const float* g1 = (const float*)d_in[5];
  const float* be1 = (const float*)d_in[6];
  const float* W2 = (const float*)d_in[7];
  const float* b2 = (const float*)d_in[8];
  const float* g2 = (const float*)d_in[9];
  const float* be2 = (const float*)d_in[10];
  float* out = (float*)d_out;

  const int* rows = ei;
  const int* cols = ei + EE;

  // d_out scratch (dead before k_bnrelu writes d_out)
  int* bcur = (int*)d_out;                                  // NBUCK ints
  unsigned short* xb = (unsigned short*)d_out + 2000000;    // byte 4.0M
  unsigned int* bbuf = (unsigned int*)((char*)d_out + 16800000);  // 6.4MB
  unsigned short* W1b = (unsigned short*)d_out + 11640000;  // byte 23.28M
  unsigned short* W2b = (unsigned short*)d_out + 11680000;  // byte 23.36M
  float* reps = (float*)d_out + 5875000;                    // byte 23.5M, 64KB
  float* sum1r = reps;
  float* sumsq1r = reps + NREP * DD;
  float* sum2r = reps + 2 * NREP * DD;
  float* sumsq2r = reps + 3 * NREP * DD;

  unsigned short* h1b = (unsigned short*)d_ws;        // aggemm1 out
  unsigned short* h2b = h1b + (size_t)NN * DD;        // gemm2 out
  float* stats = (float*)(h1b + (size_t)2 * NN * DD); // 4KB tail of d_ws
  float* scale2 = stats + 0;
  float* shift2 = stats + 128;

  // 1. prep: x/W1/W2 -> bf16, zero bcur + stat replicas
  k_prep<<<XCONV_B + 32, 256, 0, stream>>>(x, W1, W2, xb, W1b, W2b, bcur, reps);
  // 2. bin edges into fixed 16-row buckets (packed u32)
  k_bin0<<<BIN_BLOCKS, 256, 0, stream>>>(rows, cols, bcur, bbuf);
  // 3. FUSED per-bucket sort + gather aggregation + GEMM1 -> h1b, BN1 stats
  k_aggemm1<<<NBUCK, 128, 0, stream>>>(xb, eps, bcur, bbuf, W1b, b1, h1b,
                                       sum1r, sumsq1r);
  // 4. GEMM2 (BN1+ReLU on the fly) -> h2b, BN2 stats
  k_gemm2<<<GEMM_B, 256, 0, stream>>>(h1b, sum1r, sumsq1r, g1, be1, W2b, b2,
                                      h2b, sum2r, sumsq2r);
  // 5. collapse BN2 replicas into d_ws
  k_bnstats2<<<1, 128, 0, stream>>>(sum2r, sumsq2r, g2, be2, scale2, shift2);
  // 6. final BN2+ReLU -> fp32 out
  k_bnrelu<<<(NN * DD / 8) / 256, 256, 0, stream>>>(h2b, scale2, shift2, out);
}